// Round 17
// baseline (569.005 us; speedup 1.0000x reference)
//
#include <hip/hip_runtime.h>

typedef __bf16 bf16x8 __attribute__((ext_vector_type(8)));
typedef __bf16 bf16x4 __attribute__((ext_vector_type(4)));
typedef float f32x4 __attribute__((ext_vector_type(4)));

namespace {

constexpr int T_ = 64;
constexpr int N_ = 300;
constexpr int MD_ = 32;
constexpr int BG_ = 8;                        // B*G
constexpr long MROWS_ = (long)BG_ * T_ * N_;  // 153600
constexpr long FUSED_N = MROWS_ * 256;        // 39321600
constexpr int MB = 32;                        // rows per block (main kernel)

// packed-weight offsets in bf16 elements inside d_ws (after 256-byte header)
constexpr long PA1 = 0;        // adp_w1 [256][1024]
constexpr long PA2 = 262144;   // adp_w2 [1024][256]
constexpr long PF1 = 524288;   // fus_w1 [288][256]
constexpr long PF2 = 598016;   // fus_w2 [256][256]
constexpr long PN1 = 663552;   // ffn_w1 [256][1024]
constexpr long PN2 = 925696;   // ffn_w2 [1024][256]

// fast tanh-form GELU: |delta| vs erf-GELU <= ~2e-3 (under bf16 noise)
__device__ __forceinline__ float gelu_f(float x) {
  const float x2 = x * x;
  const float z2 = x * fmaf(x2, 0.07135481627f, 1.5957691216f);  // 2*z
  const float t = __builtin_amdgcn_rcpf(1.0f + __expf(z2));      // (1-tanh z)/2
  return x * (1.0f - t);
}

__device__ __forceinline__ float gelu_exact(float x) {
  return 0.5f * x * (1.0f + erff(x * 0.7071067811865476f));
}

// ---------------- mask dtype detection ----------------
__global__ void k_zero_flag(int* f) { *f = 0; }

__global__ void k_detect_mask(const unsigned char* __restrict__ m, int nbytes,
                              int* __restrict__ f) {
  int i = blockIdx.x * 256 + threadIdx.x;
  if (i < nbytes && (i & 3) != 0 && m[i] != 0) atomicOr(f, 1);
}

// ---------------- motion features (unchanged, verified) ----------------
__global__ __launch_bounds__(256)
void k_motion(const float* __restrict__ boxes, const void* __restrict__ masks,
              const int* __restrict__ times,
              const float* __restrict__ mw1, const float* __restrict__ mb1,
              const float* __restrict__ mw2, const float* __restrict__ mb2,
              float* __restrict__ motion, const int* __restrict__ flagp) {
  __shared__ int slot[4][T_];
  __shared__ int sts[4][T_];
  __shared__ float sbx[4][T_][4];
  __shared__ float otile[4][T_][MD_];
  const int tid = threadIdx.x;
  const int w = tid >> 6, l = tid & 63;
  const int traj = blockIdx.x * 4 + w;
  const int bg = traj / N_, n = traj - bg * N_;
  const int isbool = *flagp;
  const long idx = ((long)bg * T_ + l) * N_ + n;  // t = l
  const bool msk = isbool ? (((const unsigned char*)masks)[idx] != 0)
                          : (((const int*)masks)[idx] != 0);
  const bool valid = !msk;
  const int tm = times[idx];

  slot[w][l] = -1;
  sts[w][l] = 0;
  *(float4*)&sbx[w][l][0] = make_float4(0.f, 0.f, 0.f, 0.f);
  __syncthreads();
  if (valid) slot[w][tm] = l;
  __syncthreads();

  const int ot = slot[w][l];
  const bool vp = ot >= 0;
  const unsigned long long bal = __ballot(vp);
  const int cnt = __builtin_popcountll(bal);
  const int pos = __builtin_popcountll(bal & ((1ull << l) - 1ull));
  if (vp) {
    sts[w][pos] = l;
    const float4 bx = *(const float4*)(boxes + (((long)bg * T_ + ot) * N_ + n) * 4);
    *(float4*)&sbx[w][pos][0] = bx;
  }
  __syncthreads();

  const int stp = sts[w][l];
  const int stm1 = sts[w][(l + 63) & 63];
  const float4 sb = *(const float4*)&sbx[w][l][0];
  const float4 sbm = *(const float4*)&sbx[w][(l + 63) & 63][0];
  const float dt = (float)max(stp - stm1, 1);
  const float inv = 1.0f / dt;
  const bool okv = (l >= 1) && (l < cnt);
  float v0 = okv ? (sb.x - sbm.x) * inv : 0.f;
  float v1 = okv ? (sb.y - sbm.y) * inv : 0.f;
  float v2 = okv ? (sb.z - sbm.z) * inv : 0.f;
  float v3 = okv ? (sb.w - sbm.w) * inv : 0.f;
  const float p0 = __shfl_up(v0, 1, 64);
  const float p1 = __shfl_up(v1, 1, 64);
  const float p2 = __shfl_up(v2, 1, 64);
  const float p3 = __shfl_up(v3, 1, 64);
  const bool oka = (l >= 2) && (l < cnt);
  const float a0 = oka ? (v0 - p0) * inv : 0.f;
  const float a1 = oka ? (v1 - p1) * inv : 0.f;
  const float a2 = oka ? (v2 - p2) * inv : 0.f;
  const float a3 = oka ? (v3 - p3) * inv : 0.f;

  const float mv[12] = {sb.x, sb.y, sb.z, sb.w, v0, v1, v2, v3, a0, a1, a2, a3};
  float e1[16];
#pragma unroll
  for (int i = 0; i < 16; ++i) {
    float a = mb1[i];
#pragma unroll
    for (int c = 0; c < 12; ++c) a = fmaf(mv[c], mw1[c * 16 + i], a);
    e1[i] = gelu_exact(a);
  }
  float enc[32];
#pragma unroll
  for (int o = 0; o < 32; ++o) {
    float a = mb2[o];
#pragma unroll
    for (int i = 0; i < 16; ++i) a = fmaf(e1[i], mw2[i * 32 + o], a);
    enc[o] = a;
  }

#pragma unroll
  for (int c = 0; c < 32; c += 4)
    *(float4*)&otile[w][l][c] = make_float4(0.f, 0.f, 0.f, 0.f);
  __syncthreads();
  if (l < cnt && cnt >= 2) {
#pragma unroll
    for (int c = 0; c < 32; ++c) otile[w][stp][c] = enc[c];
  }
  __syncthreads();

  float* mbase = motion + ((long)bg * T_ * N_ + n) * MD_;
  const float4* srcv = (const float4*)&otile[w][l][0];
  float4* dstv = (float4*)(mbase + (long)l * N_ * MD_);
#pragma unroll
  for (int q = 0; q < 8; ++q) dstv[q] = srcv[q];
}

// ---------------- weight packing: f32 row-major -> bf16 MFMA fragments ----
// frag f = kb*(NN/16)+nt holds W[kb*32 + (l>>4)*8 + e][nt*16 + (l&15)],
// stored lane-contiguous: P[(f*64 + l)*8 + e]. Serves as B-operand (normal)
// and A-operand (swapped) -- the lane/element structures are identical.
__global__ void k_pack(const float* __restrict__ W, __bf16* __restrict__ P,
                       int K, int NN) {
  int gid = blockIdx.x * 256 + threadIdx.x;
  int total = (K >> 5) * (NN >> 4) * 64;
  if (gid >= total) return;
  int l = gid & 63, f = gid >> 6;
  int NT = NN >> 4;
  int kb = f / NT, nt = f - kb * NT;
  int krow = kb * 32 + (l >> 4) * 8;
  int col = nt * 16 + (l & 15);
  bf16x8 v;
#pragma unroll
  for (int e = 0; e < 8; ++e) v[e] = (__bf16)W[(long)(krow + e) * NN + col];
  *(bf16x8*)(P + (long)gid * 8) = v;
}

// ---- swapped-orientation producer: one [32 rows]x[128 feat] gelu'd chunk ----
// Each wave owns TWO 16-feat tiles (nt0 = r*8 + wid*2, +1): the same xf
// ds_read feeds 4 MFMAs (2 nt x 2 rt). Weight loads double-buffered 2 kb
// ahead. C-layout lane holds (x-row = l&15, 4 consecutive feats) -> one
// packed ds_write_b64 per (nt, rt) into hb[row][feat] (row stride 256B,
// byte ^ ((row&7)<<4) swizzle). K = NKB*32; if MOT, last kb reads the
// motion tile (regM) instead of regA.
template <int NKB, bool MOT, int NT>
__device__ __forceinline__ void produce_chunk(
    const char* regA, const char* regM, char* hb, const __bf16* pb1,
    const float* b1, int r, int wid, int l, int lr, int lk) {
  const int nt0 = r * 8 + wid * 2;
  f32x4 t[2][2];  // [n][rt]
#pragma unroll
  for (int n = 0; n < 2; ++n) {
    const float4 bv = *(const float4*)(b1 + (nt0 + n) * 16 + lk * 4);
    t[n][0] = f32x4{bv.x, bv.y, bv.z, bv.w};
    t[n][1] = t[n][0];
  }
  const __bf16* wp0 = pb1 + ((long)nt0 << 9) + (l << 3);
  const __bf16* wp1 = wp0 + (1 << 9);
  bf16x8 wa0 = *(const bf16x8*)(wp0);
  bf16x8 wa1 = *(const bf16x8*)(wp1);
  bf16x8 wb0 = wa0, wb1 = wa1;
  if (NKB > 1) {
    wb0 = *(const bf16x8*)(wp0 + ((long)NT << 9));
    wb1 = *(const bf16x8*)(wp1 + ((long)NT << 9));
  }
#pragma unroll
  for (int kb = 0; kb < NKB; ++kb) {
    const bf16x8 wf0 = (kb & 1) ? wb0 : wa0;
    const bf16x8 wf1 = (kb & 1) ? wb1 : wa1;
    if (kb + 2 < NKB) {
      const bf16x8 v0 = *(const bf16x8*)(wp0 + ((long)((kb + 2) * NT) << 9));
      const bf16x8 v1 = *(const bf16x8*)(wp1 + ((long)((kb + 2) * NT) << 9));
      if (kb & 1) { wb0 = v0; wb1 = v1; } else { wa0 = v0; wa1 = v1; }
    }
    __builtin_amdgcn_s_setprio(1);
#pragma unroll
    for (int rt = 0; rt < 2; ++rt) {
      const int row = rt * 16 + lr;
      bf16x8 xf;
      if (MOT && kb == NKB - 1)
        xf = *(const bf16x8*)(regM + row * 64 + ((lk ^ (row & 3)) << 4));
      else
        xf = *(const bf16x8*)(regA + row * 512 +
                              ((((kb << 2) + lk) ^ (row & 7)) << 4));
      t[0][rt] = __builtin_amdgcn_mfma_f32_16x16x32_bf16(wf0, xf, t[0][rt], 0, 0, 0);
      t[1][rt] = __builtin_amdgcn_mfma_f32_16x16x32_bf16(wf1, xf, t[1][rt], 0, 0, 0);
    }
    __builtin_amdgcn_s_setprio(0);
  }
#pragma unroll
  for (int n = 0; n < 2; ++n)
#pragma unroll
    for (int rt = 0; rt < 2; ++rt) {
      const int row = rt * 16 + lr;
      bf16x4 hv;
#pragma unroll
      for (int e = 0; e < 4; ++e) hv[e] = (__bf16)gelu_f(t[n][rt][e]);
      *(bf16x4*)(hb + row * 256 +
                 ((wid * 64 + n * 32 + lk * 8) ^ ((row & 7) << 4))) = hv;
    }
}

// ---- normal-orientation consumer: acc += chunk(K=128) @ pb2[slice][wn] ----
// A-frags via ds_read_b128 from hb (same byte-XOR swizzle as produce),
// weights direct from global (L2), double-buffered (R25-verified).
__device__ __forceinline__ void consume_chunk(const char* hb,
                                              const __bf16* pb2, int kbg0,
                                              int l, int lr, int lk, int wn,
                                              f32x4 (&acc)[2][4]) {
  const __bf16* wp = pb2 + ((long)(kbg0 * 16 + wn * 4) << 9) + (l << 3);
  bf16x8 bw0[4], bw1[4];
#pragma unroll
  for (int j = 0; j < 4; ++j) bw0[j] = *(const bf16x8*)(wp + ((long)j << 9));
#pragma unroll
  for (int kbl = 0; kbl < 4; ++kbl) {
    if (kbl < 3) {
#pragma unroll
      for (int j = 0; j < 4; ++j)
        bw1[j] = *(const bf16x8*)(wp + ((long)((kbl + 1) * 16 + j) << 9));
    }
    bf16x8 a[2];
#pragma unroll
    for (int m = 0; m < 2; ++m) {
      const int row = m * 16 + lr;
      a[m] = *(const bf16x8*)(hb + row * 256 +
                              ((kbl * 64 + lk * 16) ^ ((row & 7) << 4)));
    }
    __builtin_amdgcn_s_setprio(1);
#pragma unroll
    for (int j = 0; j < 4; ++j)
#pragma unroll
      for (int m = 0; m < 2; ++m)
        acc[m][j] = __builtin_amdgcn_mfma_f32_16x16x32_bf16(a[m], bw0[j],
                                                            acc[m][j], 0, 0, 0);
    __builtin_amdgcn_s_setprio(0);
#pragma unroll
    for (int j = 0; j < 4; ++j) bw0[j] = bw1[j];
  }
}

// ---- R26: FUSED round -- produce(r+1) interleaved 2:1 with consume(r) ----
// produce writes hbw = hb[(r+1)&1], consume reads hbr = hb[r&1]: disjoint
// buffers, no intra-round dependence. Interleaving at source level gives
// the scheduler two independent MFMA/LDS/L2 streams per wave (the win R21's
// wave-specialization wanted, without its per-role register blowup).
// Unified liveness ~140 < 170 -> no spill. Per-stream op order unchanged ->
// numerics identical. A/C phases only (NT=64, no MOT).
__device__ __forceinline__ void fused_round(
    const char* regA, char* hbw, const char* hbr, const __bf16* pb1,
    const float* b1, int rprod, const __bf16* pb2, int kbg0, int wid, int l,
    int lr, int lk, int wn, f32x4 (&acc)[2][4]) {
  constexpr int NT = 64;
  // ---- produce state ----
  const int nt0 = rprod * 8 + wid * 2;
  f32x4 t[2][2];
#pragma unroll
  for (int n = 0; n < 2; ++n) {
    const float4 bv = *(const float4*)(b1 + (nt0 + n) * 16 + lk * 4);
    t[n][0] = f32x4{bv.x, bv.y, bv.z, bv.w};
    t[n][1] = t[n][0];
  }
  const __bf16* wp0 = pb1 + ((long)nt0 << 9) + (l << 3);
  const __bf16* wp1 = wp0 + (1 << 9);
  bf16x8 wa0 = *(const bf16x8*)(wp0);
  bf16x8 wa1 = *(const bf16x8*)(wp1);
  bf16x8 wb0 = *(const bf16x8*)(wp0 + ((long)NT << 9));
  bf16x8 wb1 = *(const bf16x8*)(wp1 + ((long)NT << 9));
  // ---- consume state ----
  const __bf16* wp = pb2 + ((long)(kbg0 * 16 + wn * 4) << 9) + (l << 3);
  bf16x8 bw0[4], bw1[4];
#pragma unroll
  for (int j = 0; j < 4; ++j) bw0[j] = *(const bf16x8*)(wp + ((long)j << 9));
  // ---- interleaved main loop: 8 produce kb-steps, consume on odd kb ----
#pragma unroll
  for (int kb = 0; kb < 8; ++kb) {
    const bf16x8 wf0 = (kb & 1) ? wb0 : wa0;
    const bf16x8 wf1 = (kb & 1) ? wb1 : wa1;
    if (kb + 2 < 8) {
      const bf16x8 v0 = *(const bf16x8*)(wp0 + ((long)((kb + 2) * NT) << 9));
      const bf16x8 v1 = *(const bf16x8*)(wp1 + ((long)((kb + 2) * NT) << 9));
      if (kb & 1) { wb0 = v0; wb1 = v1; } else { wa0 = v0; wa1 = v1; }
    }
    __builtin_amdgcn_s_setprio(1);
#pragma unroll
    for (int rt = 0; rt < 2; ++rt) {
      const int row = rt * 16 + lr;
      const bf16x8 xf = *(const bf16x8*)(regA + row * 512 +
                                         ((((kb << 2) + lk) ^ (row & 7)) << 4));
      t[0][rt] = __builtin_amdgcn_mfma_f32_16x16x32_bf16(wf0, xf, t[0][rt], 0, 0, 0);
      t[1][rt] = __builtin_amdgcn_mfma_f32_16x16x32_bf16(wf1, xf, t[1][rt], 0, 0, 0);
    }
    __builtin_amdgcn_s_setprio(0);
    if (kb & 1) {
      const int kbl = kb >> 1;
      if (kbl < 3) {
#pragma unroll
        for (int j = 0; j < 4; ++j)
          bw1[j] = *(const bf16x8*)(wp + ((long)((kbl + 1) * 16 + j) << 9));
      }
      bf16x8 a[2];
#pragma unroll
      for (int m = 0; m < 2; ++m) {
        const int row = m * 16 + lr;
        a[m] = *(const bf16x8*)(hbr + row * 256 +
                                ((kbl * 64 + lk * 16) ^ ((row & 7) << 4)));
      }
      __builtin_amdgcn_s_setprio(1);
#pragma unroll
      for (int j = 0; j < 4; ++j)
#pragma unroll
        for (int m = 0; m < 2; ++m)
          acc[m][j] = __builtin_amdgcn_mfma_f32_16x16x32_bf16(a[m], bw0[j],
                                                              acc[m][j], 0, 0, 0);
      __builtin_amdgcn_s_setprio(0);
#pragma unroll
      for (int j = 0; j < 4; ++j) bw0[j] = bw1[j];
    }
  }
  // ---- produce epilogue: gelu + packed store into hbw ----
#pragma unroll
  for (int n = 0; n < 2; ++n)
#pragma unroll
    for (int rt = 0; rt < 2; ++rt) {
      const int row = rt * 16 + lr;
      bf16x4 hv;
#pragma unroll
      for (int e = 0; e < 4; ++e) hv[e] = (__bf16)gelu_f(t[n][rt][e]);
      *(bf16x4*)(hbw + row * 256 +
                 ((wid * 64 + n * 32 + lk * 8) ^ ((row & 7) << 4))) = hv;
    }
}

// ---------------- fused MFMA row pipeline ----------------
// R26: R25 (562us e2e best: (256,3), widened produce, consume dbuf) with
// the A/C rounds FUSED: produce(r+1) and consume(r) interleaved 2:1 in one
// wave (disjoint hb buffers -> legal; gives the scheduler two independent
// MFMA/LDS/L2 streams, the R21 goal without its register blowup).
// Liveness ~140 < 170 -> no spill. Barrier positions + per-stream op order
// unchanged -> numerics identical.
__global__ __launch_bounds__(256, 3)
void k_mfma(const float* __restrict__ feats, const float* __restrict__ motion,
            const __bf16* __restrict__ pw,
            const float* __restrict__ ba1, const float* __restrict__ ba2,
            const float* __restrict__ ng, const float* __restrict__ nb,
            const float* __restrict__ bf1, const float* __restrict__ bf2,
            const float* __restrict__ bn1, const float* __restrict__ bn2,
            const float* __restrict__ fg, const float* __restrict__ fb,
            float* __restrict__ out) {
  __shared__ __align__(16) char smem[35840];
  char* regA = smem;             // [32][256] bf16 swizzled: x / LN1 / f
  char* hb0 = smem + 16384;      // h/g1 chunk buffer 0: [32][128] bf16
  char* hb1 = smem + 24576;      // h/g1 chunk buffer 1
  char* regM = smem + 32768;     // [32][32] bf16 motion tile
  float* redp = (float*)(smem + 34816);  // [32][4][2] LN partials

  const int tid = threadIdx.x;
  const int l = tid & 63, wid = tid >> 6;  // 4 waves
  const int lr = l & 15, lk = l >> 4;
  const int wn = wid;          // 0..3 : 64-col slice (consume)
  const int colb = wn * 64;
  const long rowbase = (long)blockIdx.x * MB;

  const __bf16* pa1 = pw + PA1;
  const __bf16* pa2 = pw + PA2;
  const __bf16* pf1 = pw + PF1;
  const __bf16* pf2 = pw + PF2;
  const __bf16* pn1 = pw + PN1;
  const __bf16* pn2 = pw + PN2;

  // fragment-layout LN stats: mean/rstd per owned row (m,e)
  auto ln_stats = [&](const f32x4 (&acc)[2][4], float (&mean)[2][4],
                      float (&rstd)[2][4]) {
    float s1[2][4], s2[2][4];
#pragma unroll
    for (int m = 0; m < 2; ++m)
#pragma unroll
      for (int e = 0; e < 4; ++e) { s1[m][e] = 0.f; s2[m][e] = 0.f; }
#pragma unroll
    for (int m = 0; m < 2; ++m)
#pragma unroll
      for (int j = 0; j < 4; ++j)
#pragma unroll
        for (int e = 0; e < 4; ++e) {
          s1[m][e] += acc[m][j][e];
          s2[m][e] += acc[m][j][e] * acc[m][j][e];
        }
#pragma unroll
    for (int o = 1; o < 16; o <<= 1)
#pragma unroll
      for (int m = 0; m < 2; ++m)
#pragma unroll
        for (int e = 0; e < 4; ++e) {
          s1[m][e] += __shfl_xor(s1[m][e], o);
          s2[m][e] += __shfl_xor(s2[m][e], o);
        }
    if (lr == 0) {
#pragma unroll
      for (int m = 0; m < 2; ++m)
#pragma unroll
        for (int e = 0; e < 4; ++e) {
          const int row = m * 16 + lk * 4 + e;
          redp[(row * 4 + wn) * 2 + 0] = s1[m][e];
          redp[(row * 4 + wn) * 2 + 1] = s2[m][e];
        }
    }
    __syncthreads();
#pragma unroll
    for (int m = 0; m < 2; ++m)
#pragma unroll
      for (int e = 0; e < 4; ++e) {
        const int row = m * 16 + lk * 4 + e;
        const float S1 = redp[(row * 4 + 0) * 2] + redp[(row * 4 + 1) * 2] +
                         redp[(row * 4 + 2) * 2] + redp[(row * 4 + 3) * 2];
        const float S2 = redp[(row * 4 + 0) * 2 + 1] + redp[(row * 4 + 1) * 2 + 1] +
                         redp[(row * 4 + 2) * 2 + 1] + redp[(row * 4 + 3) * 2 + 1];
        const float mu = S1 * (1.0f / 256.0f);
        const float var = S2 * (1.0f / 256.0f) - mu * mu;
        mean[m][e] = mu;
        rstd[m][e] = rsqrtf(var + 1e-5f);
      }
  };

  f32x4 acc2[2][4];
  // ---- init acc2 = x + ba2 (residual + bias folded into accumulator) ----
#pragma unroll
  for (int j = 0; j < 4; ++j) {
    const int col = colb + j * 16 + lr;
    const float bv = ba2[col];
#pragma unroll
    for (int m = 0; m < 2; ++m)
#pragma unroll
      for (int e = 0; e < 4; ++e) {
        const int row = m * 16 + lk * 4 + e;
        acc2[m][j][e] = bv + feats[(rowbase + row) * 256 + col];
      }
  }
  // ---- stage x (bf16, swizzled) into regA ----
#pragma unroll
  for (int it = 0; it < 4; ++it) {
    const int c = tid + it * 256;  // chunk id, 1024 total
    const int row = c >> 5, cc = c & 31;
    const float* src = feats + (rowbase + row) * 256 + cc * 8;
    bf16x8 v;
#pragma unroll
    for (int e = 0; e < 8; ++e) v[e] = (__bf16)src[e];
    *(bf16x8*)(regA + row * 512 + ((cc ^ (row & 7)) << 4)) = v;
  }
  __syncthreads();

  // ============ A-phase: x -> h -> adp out (8 rounds, 7 fused) ============
  produce_chunk<8, false, 64>(regA, regM, hb0, pa1, ba1, 0, wid, l, lr, lk);
  __syncthreads();
#pragma unroll 1
  for (int r = 0; r < 7; ++r) {
    fused_round(regA, ((r + 1) & 1) ? hb1 : hb0, (r & 1) ? hb1 : hb0, pa1, ba1,
                r + 1, pa2, r * 4, wid, l, lr, lk, wn, acc2);
    __syncthreads();
  }
  consume_chunk(hb1, pa2, 28, l, lr, lk, wn, acc2);
  __syncthreads();

  // ---- LN1 in fragment layout -> regA bf16; stage motion -> regM ----
  {
    float mean[2][4], rstd[2][4];
    ln_stats(acc2, mean, rstd);
#pragma unroll
    for (int j = 0; j < 4; ++j) {
      const int col = colb + j * 16 + lr;
      const float gv = ng[col], bv = nb[col];
#pragma unroll
      for (int m = 0; m < 2; ++m)
#pragma unroll
        for (int e = 0; e < 4; ++e) {
          const int row = m * 16 + lk * 4 + e;
          const float v = (acc2[m][j][e] - mean[m][e]) * rstd[m][e] * gv + bv;
          *(__bf16*)(regA + row * 512 + (((col >> 3) ^ (row & 7)) << 4) +
                     ((col & 7) << 1)) = (__bf16)v;
        }
    }
    if (tid < 128) {  // motion tile -> regM; 32x32 bf16
      const int row = tid >> 2, cc = tid & 3;
      const float* src = motion + (rowbase + row) * 32 + cc * 8;
      bf16x8 v;
#pragma unroll
      for (int e = 0; e < 8; ++e) v[e] = (__bf16)src[e];
      *(bf16x8*)(regM + row * 64 + ((cc ^ (row & 3)) << 4)) = v;
    }
  }
  __syncthreads();

  // ====== B-phase: fus MLP (2 pipelined rounds, K=288 w/ motion) ======
  // acc2's A-phase value is DEAD here (consumed by ln_stats/LN1 above) --
  // reused as the B2 accumulator (R19).
  {
#pragma unroll
    for (int j = 0; j < 4; ++j) {
      const float bv = bf2[colb + j * 16 + lr];
#pragma unroll
      for (int m = 0; m < 2; ++m) acc2[m][j] = {bv, bv, bv, bv};
    }
    produce_chunk<9, true, 16>(regA, regM, hb0, pf1, bf1, 0, wid, l, lr, lk);
    __syncthreads();
    produce_chunk<9, true, 16>(regA, regM, hb1, pf1, bf1, 1, wid, l, lr, lk);
    consume_chunk(hb0, pf2, 0, l, lr, lk, wn, acc2);
    __syncthreads();
    consume_chunk(hb1, pf2, 4, l, lr, lk, wn, acc2);
    __syncthreads();
    // tail: f -> regA (C1 input, bf16) ; acc2 = f + bn2 (in place)
#pragma unroll
    for (int j = 0; j < 4; ++j) {
      const int col = colb + j * 16 + lr;
      const float bv = bn2[col];
#pragma unroll
      for (int m = 0; m < 2; ++m)
#pragma unroll
        for (int e = 0; e < 4; ++e) {
          const int row = m * 16 + lk * 4 + e;
          const float fv = acc2[m][j][e];
          *(__bf16*)(regA + row * 512 + (((col >> 3) ^ (row & 7)) << 4) +
                     ((col & 7) << 1)) = (__bf16)fv;  // C1 input
          acc2[m][j][e] = fv + bv;  // residual + bias folded into C accum
        }
    }
  }
  __syncthreads();

  // ============ C-phase: ffn on f (8 rounds, 7 fused) ============
  produce_chunk<8, false, 64>(regA, regM, hb0, pn1, bn1, 0, wid, l, lr, lk);
  __syncthreads();
#pragma unroll 1
  for (int r = 0; r < 7; ++r) {
    fused_round(regA, ((r + 1) & 1) ? hb1 : hb0, (r & 1) ? hb1 : hb0, pn1, bn1,
                r + 1, pn2, r * 4, wid, l, lr, lk, wn, acc2);
    __syncthreads();
  }
  consume_chunk(hb1, pn2, 28, l, lr, lk, wn, acc2);
  __syncthreads();

  // ---- LN2 in fragment layout -> global out ----
  {
    float mean[2][4], rstd[2][4];
    ln_stats(acc2, mean, rstd);
#pragma unroll
    for (int j = 0; j < 4; ++j) {
      const int col = colb + j * 16 + lr;
      const float gv = fg[col], bv = fb[col];
#pragma unroll
      for (int m = 0; m < 2; ++m)
#pragma unroll
        for (int e = 0; e < 4; ++e) {
          const int row = m * 16 + lk * 4 + e;
          out[(rowbase + row) * 256 + col] =
              (acc2[m][j][e] - mean[m][e]) * rstd[m][e] * gv + bv;
        }
    }
  }
}

}  // namespace

extern "C" void kernel_launch(void* const* d_in, const int* in_sizes, int n_in,
                              void* d_out, int out_size, void* d_ws, size_t ws_size,
                              hipStream_t stream) {
  const float* feats = (const float*)d_in[0];
  const float* boxes = (const float*)d_in[1];
  const void*  masks = d_in[2];
  const int*   times = (const int*)d_in[3];
  const float* wa1 = (const float*)d_in[4];
  const float* ba1 = (const float*)d_in[5];
  const float* wa2 = (const float*)d_in[6];
  const float* ba2 = (const float*)d_in[7];
  const float* ng  = (const float*)d_in[8];
  const float* nb  = (const float*)d_in[9];
  const float* mw1 = (const float*)d_in[10];
  const float* mb1 = (const float*)d_in[11];
  const float* mw2 = (const float*)d_in[12];
  const float* mb2 = (const float*)d_in[13];
  const float* wf1 = (const float*)d_in[14];
  const float* bf1 = (const float*)d_in[15];
  const float* wf2 = (const float*)d_in[16];
  const float* bf2 = (const float*)d_in[17];
  const float* wn1 = (const float*)d_in[18];
  const float* bn1 = (const float*)d_in[19];
  const float* wn2 = (const float*)d_in[20];
  const float* bn2 = (const float*)d_in[21];
  const float* fg  = (const float*)d_in[22];
  const float* fb  = (const float*)d_in[23];

  float* out_fused = (float*)d_out;
  float* out_motion = out_fused + FUSED_N;
  int* flag = (int*)d_ws;
  __bf16* pwp = (__bf16*)((char*)d_ws + 256);

  const int mask_elems = in_sizes[2];  // 153600

  k_zero_flag<<<1, 1, 0, stream>>>(flag);
  k_detect_mask<<<(mask_elems + 255) / 256, 256, 0, stream>>>(
      (const unsigned char*)masks, mask_elems, flag);
  k_motion<<<(BG_ * N_) / 4, 256, 0, stream>>>(boxes, masks, times, mw1, mb1, mw2,
                                               mb2, out_motion, flag);

  auto packn = [&](const float* W, long off, int K, int NN) {
    const int total = (K / 32) * (NN / 16) * 64;
    k_pack<<<(total + 255) / 256, 256, 0, stream>>>(W, pwp + off, K, NN);
  };
  packn(wa1, PA1, 256, 1024);
  packn(wa2, PA2, 1024, 256);
  packn(wf1, PF1, 288, 256);
  packn(wf2, PF2, 256, 256);
  packn(wn1, PN1, 256, 1024);
  packn(wn2, PN2, 1024, 256);

  k_mfma<<<(int)(MROWS_ / MB), 256, 0, stream>>>(
      feats, out_motion, pwp, ba1, ba2, ng, nb, bf1, bf2, bn1, bn2, fg, fb,
      out_fused);
}

// Round 18
// 561.776 us; speedup vs baseline: 1.0129x; 1.0129x over previous
//
#include <hip/hip_runtime.h>

typedef __bf16 bf16x8 __attribute__((ext_vector_type(8)));
typedef __bf16 bf16x4 __attribute__((ext_vector_type(4)));
typedef float f32x4 __attribute__((ext_vector_type(4)));

namespace {

constexpr int T_ = 64;
constexpr int N_ = 300;
constexpr int MD_ = 32;
constexpr int BG_ = 8;                        // B*G
constexpr long MROWS_ = (long)BG_ * T_ * N_;  // 153600
constexpr long FUSED_N = MROWS_ * 256;        // 39321600
constexpr int MB = 32;                        // rows per block (main kernel)

// packed-weight offsets in bf16 elements inside d_ws (after 256-byte header)
constexpr long PA1 = 0;        // adp_w1 [256][1024]
constexpr long PA2 = 262144;   // adp_w2 [1024][256]
constexpr long PF1 = 524288;   // fus_w1 [288][256]
constexpr long PF2 = 598016;   // fus_w2 [256][256]
constexpr long PN1 = 663552;   // ffn_w1 [256][1024]
constexpr long PN2 = 925696;   // ffn_w2 [1024][256]

// fast tanh-form GELU: |delta| vs erf-GELU <= ~2e-3 (under bf16 noise)
__device__ __forceinline__ float gelu_f(float x) {
  const float x2 = x * x;
  const float z2 = x * fmaf(x2, 0.07135481627f, 1.5957691216f);  // 2*z
  const float t = __builtin_amdgcn_rcpf(1.0f + __expf(z2));      // (1-tanh z)/2
  return x * (1.0f - t);
}

__device__ __forceinline__ float gelu_exact(float x) {
  return 0.5f * x * (1.0f + erff(x * 0.7071067811865476f));
}

// ---------------- mask dtype detection ----------------
__global__ void k_zero_flag(int* f) { *f = 0; }

__global__ void k_detect_mask(const unsigned char* __restrict__ m, int nbytes,
                              int* __restrict__ f) {
  int i = blockIdx.x * 256 + threadIdx.x;
  if (i < nbytes && (i & 3) != 0 && m[i] != 0) atomicOr(f, 1);
}

// ---------------- motion features (unchanged, verified) ----------------
__global__ __launch_bounds__(256)
void k_motion(const float* __restrict__ boxes, const void* __restrict__ masks,
              const int* __restrict__ times,
              const float* __restrict__ mw1, const float* __restrict__ mb1,
              const float* __restrict__ mw2, const float* __restrict__ mb2,
              float* __restrict__ motion, const int* __restrict__ flagp) {
  __shared__ int slot[4][T_];
  __shared__ int sts[4][T_];
  __shared__ float sbx[4][T_][4];
  __shared__ float otile[4][T_][MD_];
  const int tid = threadIdx.x;
  const int w = tid >> 6, l = tid & 63;
  const int traj = blockIdx.x * 4 + w;
  const int bg = traj / N_, n = traj - bg * N_;
  const int isbool = *flagp;
  const long idx = ((long)bg * T_ + l) * N_ + n;  // t = l
  const bool msk = isbool ? (((const unsigned char*)masks)[idx] != 0)
                          : (((const int*)masks)[idx] != 0);
  const bool valid = !msk;
  const int tm = times[idx];

  slot[w][l] = -1;
  sts[w][l] = 0;
  *(float4*)&sbx[w][l][0] = make_float4(0.f, 0.f, 0.f, 0.f);
  __syncthreads();
  if (valid) slot[w][tm] = l;
  __syncthreads();

  const int ot = slot[w][l];
  const bool vp = ot >= 0;
  const unsigned long long bal = __ballot(vp);
  const int cnt = __builtin_popcountll(bal);
  const int pos = __builtin_popcountll(bal & ((1ull << l) - 1ull));
  if (vp) {
    sts[w][pos] = l;
    const float4 bx = *(const float4*)(boxes + (((long)bg * T_ + ot) * N_ + n) * 4);
    *(float4*)&sbx[w][pos][0] = bx;
  }
  __syncthreads();

  const int stp = sts[w][l];
  const int stm1 = sts[w][(l + 63) & 63];
  const float4 sb = *(const float4*)&sbx[w][l][0];
  const float4 sbm = *(const float4*)&sbx[w][(l + 63) & 63][0];
  const float dt = (float)max(stp - stm1, 1);
  const float inv = 1.0f / dt;
  const bool okv = (l >= 1) && (l < cnt);
  float v0 = okv ? (sb.x - sbm.x) * inv : 0.f;
  float v1 = okv ? (sb.y - sbm.y) * inv : 0.f;
  float v2 = okv ? (sb.z - sbm.z) * inv : 0.f;
  float v3 = okv ? (sb.w - sbm.w) * inv : 0.f;
  const float p0 = __shfl_up(v0, 1, 64);
  const float p1 = __shfl_up(v1, 1, 64);
  const float p2 = __shfl_up(v2, 1, 64);
  const float p3 = __shfl_up(v3, 1, 64);
  const bool oka = (l >= 2) && (l < cnt);
  const float a0 = oka ? (v0 - p0) * inv : 0.f;
  const float a1 = oka ? (v1 - p1) * inv : 0.f;
  const float a2 = oka ? (v2 - p2) * inv : 0.f;
  const float a3 = oka ? (v3 - p3) * inv : 0.f;

  const float mv[12] = {sb.x, sb.y, sb.z, sb.w, v0, v1, v2, v3, a0, a1, a2, a3};
  float e1[16];
#pragma unroll
  for (int i = 0; i < 16; ++i) {
    float a = mb1[i];
#pragma unroll
    for (int c = 0; c < 12; ++c) a = fmaf(mv[c], mw1[c * 16 + i], a);
    e1[i] = gelu_exact(a);
  }
  float enc[32];
#pragma unroll
  for (int o = 0; o < 32; ++o) {
    float a = mb2[o];
#pragma unroll
    for (int i = 0; i < 16; ++i) a = fmaf(e1[i], mw2[i * 32 + o], a);
    enc[o] = a;
  }

#pragma unroll
  for (int c = 0; c < 32; c += 4)
    *(float4*)&otile[w][l][c] = make_float4(0.f, 0.f, 0.f, 0.f);
  __syncthreads();
  if (l < cnt && cnt >= 2) {
#pragma unroll
    for (int c = 0; c < 32; ++c) otile[w][stp][c] = enc[c];
  }
  __syncthreads();

  float* mbase = motion + ((long)bg * T_ * N_ + n) * MD_;
  const float4* srcv = (const float4*)&otile[w][l][0];
  float4* dstv = (float4*)(mbase + (long)l * N_ * MD_);
#pragma unroll
  for (int q = 0; q < 8; ++q) dstv[q] = srcv[q];
}

// ---------------- weight packing: f32 row-major -> bf16 MFMA fragments ----
// frag f = kb*(NN/16)+nt holds W[kb*32 + (l>>4)*8 + e][nt*16 + (l&15)],
// stored lane-contiguous: P[(f*64 + l)*8 + e]. Serves as B-operand (normal)
// and A-operand (swapped) -- the lane/element structures are identical.
__global__ void k_pack(const float* __restrict__ W, __bf16* __restrict__ P,
                       int K, int NN) {
  int gid = blockIdx.x * 256 + threadIdx.x;
  int total = (K >> 5) * (NN >> 4) * 64;
  if (gid >= total) return;
  int l = gid & 63, f = gid >> 6;
  int NT = NN >> 4;
  int kb = f / NT, nt = f - kb * NT;
  int krow = kb * 32 + (l >> 4) * 8;
  int col = nt * 16 + (l & 15);
  bf16x8 v;
#pragma unroll
  for (int e = 0; e < 8; ++e) v[e] = (__bf16)W[(long)(krow + e) * NN + col];
  *(bf16x8*)(P + (long)gid * 8) = v;
}

// ---- swapped-orientation producer: one [32 rows]x[128 feat] gelu'd chunk ----
// Each wave owns TWO 16-feat tiles (nt0 = r*8 + wid*2, +1): the same xf
// ds_read feeds 4 MFMAs (2 nt x 2 rt). Weight loads double-buffered 2 kb
// ahead (verified R22). C-layout lane holds (x-row = l&15, 4 consecutive
// feats) -> one packed ds_write_b64 per (nt, rt) into hb[row][feat] (row
// stride 256B, byte ^ ((row&7)<<4) swizzle -- the R14-verified pattern).
// K = NKB*32; if MOT, last kb reads the motion tile (regM) instead of regA.
template <int NKB, bool MOT, int NT>
__device__ __forceinline__ void produce_chunk(
    const char* regA, const char* regM, char* hb, const __bf16* pb1,
    const float* b1, int r, int wid, int l, int lr, int lk) {
  const int nt0 = r * 8 + wid * 2;
  f32x4 t[2][2];  // [n][rt]
#pragma unroll
  for (int n = 0; n < 2; ++n) {
    const float4 bv = *(const float4*)(b1 + (nt0 + n) * 16 + lk * 4);
    t[n][0] = f32x4{bv.x, bv.y, bv.z, bv.w};
    t[n][1] = t[n][0];
  }
  const __bf16* wp0 = pb1 + ((long)nt0 << 9) + (l << 3);
  const __bf16* wp1 = wp0 + (1 << 9);
  bf16x8 wa0 = *(const bf16x8*)(wp0);
  bf16x8 wa1 = *(const bf16x8*)(wp1);
  bf16x8 wb0 = wa0, wb1 = wa1;
  if (NKB > 1) {
    wb0 = *(const bf16x8*)(wp0 + ((long)NT << 9));
    wb1 = *(const bf16x8*)(wp1 + ((long)NT << 9));
  }
#pragma unroll
  for (int kb = 0; kb < NKB; ++kb) {
    const bf16x8 wf0 = (kb & 1) ? wb0 : wa0;
    const bf16x8 wf1 = (kb & 1) ? wb1 : wa1;
    if (kb + 2 < NKB) {
      const bf16x8 v0 = *(const bf16x8*)(wp0 + ((long)((kb + 2) * NT) << 9));
      const bf16x8 v1 = *(const bf16x8*)(wp1 + ((long)((kb + 2) * NT) << 9));
      if (kb & 1) { wb0 = v0; wb1 = v1; } else { wa0 = v0; wa1 = v1; }
    }
    __builtin_amdgcn_s_setprio(1);
#pragma unroll
    for (int rt = 0; rt < 2; ++rt) {
      const int row = rt * 16 + lr;
      bf16x8 xf;
      if (MOT && kb == NKB - 1)
        xf = *(const bf16x8*)(regM + row * 64 + ((lk ^ (row & 3)) << 4));
      else
        xf = *(const bf16x8*)(regA + row * 512 +
                              ((((kb << 2) + lk) ^ (row & 7)) << 4));
      t[0][rt] = __builtin_amdgcn_mfma_f32_16x16x32_bf16(wf0, xf, t[0][rt], 0, 0, 0);
      t[1][rt] = __builtin_amdgcn_mfma_f32_16x16x32_bf16(wf1, xf, t[1][rt], 0, 0, 0);
    }
    __builtin_amdgcn_s_setprio(0);
  }
#pragma unroll
  for (int n = 0; n < 2; ++n)
#pragma unroll
    for (int rt = 0; rt < 2; ++rt) {
      const int row = rt * 16 + lr;
      bf16x4 hv;
#pragma unroll
      for (int e = 0; e < 4; ++e) hv[e] = (__bf16)gelu_f(t[n][rt][e]);
      *(bf16x4*)(hb + row * 256 +
                 ((wid * 64 + n * 32 + lk * 8) ^ ((row & 7) << 4))) = hv;
    }
}

// ---- normal-orientation consumer: acc += chunk(K=128) @ pb2[slice][wn] ----
// A-frags via ds_read_b128 from hb (same byte-XOR swizzle as produce),
// weights direct from global (L2), double-buffered (R25-verified: R22 used
// only 132/170 unified regs, the +16 ILP regs fit and hide L2 latency).
__device__ __forceinline__ void consume_chunk(const char* hb,
                                              const __bf16* pb2, int kbg0,
                                              int l, int lr, int lk, int wn,
                                              f32x4 (&acc)[2][4]) {
  const __bf16* wp = pb2 + ((long)(kbg0 * 16 + wn * 4) << 9) + (l << 3);
  bf16x8 bw0[4], bw1[4];
#pragma unroll
  for (int j = 0; j < 4; ++j) bw0[j] = *(const bf16x8*)(wp + ((long)j << 9));
#pragma unroll
  for (int kbl = 0; kbl < 4; ++kbl) {
    if (kbl < 3) {
#pragma unroll
      for (int j = 0; j < 4; ++j)
        bw1[j] = *(const bf16x8*)(wp + ((long)((kbl + 1) * 16 + j) << 9));
    }
    bf16x8 a[2];
#pragma unroll
    for (int m = 0; m < 2; ++m) {
      const int row = m * 16 + lr;
      a[m] = *(const bf16x8*)(hb + row * 256 +
                              ((kbl * 64 + lk * 16) ^ ((row & 7) << 4)));
    }
    __builtin_amdgcn_s_setprio(1);
#pragma unroll
    for (int j = 0; j < 4; ++j)
#pragma unroll
      for (int m = 0; m < 2; ++m)
        acc[m][j] = __builtin_amdgcn_mfma_f32_16x16x32_bf16(a[m], bw0[j],
                                                            acc[m][j], 0, 0, 0);
    __builtin_amdgcn_s_setprio(0);
#pragma unroll
    for (int j = 0; j < 4; ++j) bw0[j] = bw1[j];
  }
}

// ---------------- fused MFMA row pipeline ----------------
// R27 = R25 verbatim, the session's verified optimum (572us kernel / 562us
// e2e; baseline was 828). Configuration: MB=32, 256 threads, (256,3) ->
// 170 unified regs (the unique spill-free point -- every >=4-waves/SIMD
// config spills, R15/R17/R23), produce widened 2-nt (R22 optimum; 4-nt
// regressed R24), consume weight double-buffer (R25 win). All structural
// perturbations tested and priced: wave specialization (R21 -55us),
// in-wave fusion (R26 -6us + spill), counted-vmcnt pipeline (R10 null).
// Traffic at ideal (FETCH 205 / WRITE 201 MB), conflicts at the
// ds_read_b128-inherent level, MfmaUtil ~30 / VALU ~39 / HBM ~9%:
// a latency plateau of this decomposition, not a pipe roofline.
__global__ __launch_bounds__(256, 3)
void k_mfma(const float* __restrict__ feats, const float* __restrict__ motion,
            const __bf16* __restrict__ pw,
            const float* __restrict__ ba1, const float* __restrict__ ba2,
            const float* __restrict__ ng, const float* __restrict__ nb,
            const float* __restrict__ bf1, const float* __restrict__ bf2,
            const float* __restrict__ bn1, const float* __restrict__ bn2,
            const float* __restrict__ fg, const float* __restrict__ fb,
            float* __restrict__ out) {
  __shared__ __align__(16) char smem[35840];
  char* regA = smem;             // [32][256] bf16 swizzled: x / LN1 / f
  char* hb0 = smem + 16384;      // h/g1 chunk buffer 0: [32][128] bf16
  char* hb1 = smem + 24576;      // h/g1 chunk buffer 1
  char* regM = smem + 32768;     // [32][32] bf16 motion tile
  float* redp = (float*)(smem + 34816);  // [32][4][2] LN partials

  const int tid = threadIdx.x;
  const int l = tid & 63, wid = tid >> 6;  // 4 waves
  const int lr = l & 15, lk = l >> 4;
  const int wn = wid;          // 0..3 : 64-col slice (consume)
  const int colb = wn * 64;
  const long rowbase = (long)blockIdx.x * MB;

  const __bf16* pa1 = pw + PA1;
  const __bf16* pa2 = pw + PA2;
  const __bf16* pf1 = pw + PF1;
  const __bf16* pf2 = pw + PF2;
  const __bf16* pn1 = pw + PN1;
  const __bf16* pn2 = pw + PN2;

  // fragment-layout LN stats: mean/rstd per owned row (m,e)
  auto ln_stats = [&](const f32x4 (&acc)[2][4], float (&mean)[2][4],
                      float (&rstd)[2][4]) {
    float s1[2][4], s2[2][4];
#pragma unroll
    for (int m = 0; m < 2; ++m)
#pragma unroll
      for (int e = 0; e < 4; ++e) { s1[m][e] = 0.f; s2[m][e] = 0.f; }
#pragma unroll
    for (int m = 0; m < 2; ++m)
#pragma unroll
      for (int j = 0; j < 4; ++j)
#pragma unroll
        for (int e = 0; e < 4; ++e) {
          s1[m][e] += acc[m][j][e];
          s2[m][e] += acc[m][j][e] * acc[m][j][e];
        }
#pragma unroll
    for (int o = 1; o < 16; o <<= 1)
#pragma unroll
      for (int m = 0; m < 2; ++m)
#pragma unroll
        for (int e = 0; e < 4; ++e) {
          s1[m][e] += __shfl_xor(s1[m][e], o);
          s2[m][e] += __shfl_xor(s2[m][e], o);
        }
    if (lr == 0) {
#pragma unroll
      for (int m = 0; m < 2; ++m)
#pragma unroll
        for (int e = 0; e < 4; ++e) {
          const int row = m * 16 + lk * 4 + e;
          redp[(row * 4 + wn) * 2 + 0] = s1[m][e];
          redp[(row * 4 + wn) * 2 + 1] = s2[m][e];
        }
    }
    __syncthreads();
#pragma unroll
    for (int m = 0; m < 2; ++m)
#pragma unroll
      for (int e = 0; e < 4; ++e) {
        const int row = m * 16 + lk * 4 + e;
        const float S1 = redp[(row * 4 + 0) * 2] + redp[(row * 4 + 1) * 2] +
                         redp[(row * 4 + 2) * 2] + redp[(row * 4 + 3) * 2];
        const float S2 = redp[(row * 4 + 0) * 2 + 1] + redp[(row * 4 + 1) * 2 + 1] +
                         redp[(row * 4 + 2) * 2 + 1] + redp[(row * 4 + 3) * 2 + 1];
        const float mu = S1 * (1.0f / 256.0f);
        const float var = S2 * (1.0f / 256.0f) - mu * mu;
        mean[m][e] = mu;
        rstd[m][e] = rsqrtf(var + 1e-5f);
      }
  };

  f32x4 acc2[2][4];
  // ---- init acc2 = x + ba2 (residual + bias folded into accumulator) ----
#pragma unroll
  for (int j = 0; j < 4; ++j) {
    const int col = colb + j * 16 + lr;
    const float bv = ba2[col];
#pragma unroll
    for (int m = 0; m < 2; ++m)
#pragma unroll
      for (int e = 0; e < 4; ++e) {
        const int row = m * 16 + lk * 4 + e;
        acc2[m][j][e] = bv + feats[(rowbase + row) * 256 + col];
      }
  }
  // ---- stage x (bf16, swizzled) into regA ----
#pragma unroll
  for (int it = 0; it < 4; ++it) {
    const int c = tid + it * 256;  // chunk id, 1024 total
    const int row = c >> 5, cc = c & 31;
    const float* src = feats + (rowbase + row) * 256 + cc * 8;
    bf16x8 v;
#pragma unroll
    for (int e = 0; e < 8; ++e) v[e] = (__bf16)src[e];
    *(bf16x8*)(regA + row * 512 + ((cc ^ (row & 7)) << 4)) = v;
  }
  __syncthreads();

  // ============ A-phase: x -> h -> adp out (8 pipelined rounds) ============
  produce_chunk<8, false, 64>(regA, regM, hb0, pa1, ba1, 0, wid, l, lr, lk);
  __syncthreads();
#pragma unroll 1
  for (int r = 0; r < 8; ++r) {
    if (r < 7)
      produce_chunk<8, false, 64>(regA, regM, ((r + 1) & 1) ? hb1 : hb0, pa1,
                                  ba1, r + 1, wid, l, lr, lk);
    consume_chunk((r & 1) ? hb1 : hb0, pa2, r * 4, l, lr, lk, wn, acc2);
    __syncthreads();
  }

  // ---- LN1 in fragment layout -> regA bf16; stage motion -> regM ----
  {
    float mean[2][4], rstd[2][4];
    ln_stats(acc2, mean, rstd);
#pragma unroll
    for (int j = 0; j < 4; ++j) {
      const int col = colb + j * 16 + lr;
      const float gv = ng[col], bv = nb[col];
#pragma unroll
      for (int m = 0; m < 2; ++m)
#pragma unroll
        for (int e = 0; e < 4; ++e) {
          const int row = m * 16 + lk * 4 + e;
          const float v = (acc2[m][j][e] - mean[m][e]) * rstd[m][e] * gv + bv;
          *(__bf16*)(regA + row * 512 + (((col >> 3) ^ (row & 7)) << 4) +
                     ((col & 7) << 1)) = (__bf16)v;
        }
    }
    if (tid < 128) {  // motion tile -> regM; 32x32 bf16
      const int row = tid >> 2, cc = tid & 3;
      const float* src = motion + (rowbase + row) * 32 + cc * 8;
      bf16x8 v;
#pragma unroll
      for (int e = 0; e < 8; ++e) v[e] = (__bf16)src[e];
      *(bf16x8*)(regM + row * 64 + ((cc ^ (row & 3)) << 4)) = v;
    }
  }
  __syncthreads();

  // ====== B-phase: fus MLP (2 pipelined rounds, K=288 w/ motion) ======
  // acc2's A-phase value is DEAD here (consumed by ln_stats/LN1 above) --
  // reused as the B2 accumulator (R19).
  {
#pragma unroll
    for (int j = 0; j < 4; ++j) {
      const float bv = bf2[colb + j * 16 + lr];
#pragma unroll
      for (int m = 0; m < 2; ++m) acc2[m][j] = {bv, bv, bv, bv};
    }
    produce_chunk<9, true, 16>(regA, regM, hb0, pf1, bf1, 0, wid, l, lr, lk);
    __syncthreads();
    produce_chunk<9, true, 16>(regA, regM, hb1, pf1, bf1, 1, wid, l, lr, lk);
    consume_chunk(hb0, pf2, 0, l, lr, lk, wn, acc2);
    __syncthreads();
    consume_chunk(hb1, pf2, 4, l, lr, lk, wn, acc2);
    __syncthreads();
    // tail: f -> regA (C1 input, bf16) ; acc2 = f + bn2 (in place)
#pragma unroll
    for (int j = 0; j < 4; ++j) {
      const int col = colb + j * 16 + lr;
      const float bv = bn2[col];
#pragma unroll
      for (int m = 0; m < 2; ++m)
#pragma unroll
        for (int e = 0; e < 4; ++e) {
          const int row = m * 16 + lk * 4 + e;
          const float fv = acc2[m][j][e];
          *(__bf16*)(regA + row * 512 + (((col >> 3) ^ (row & 7)) << 4) +
                     ((col & 7) << 1)) = (__bf16)fv;  // C1 input
          acc2[m][j][e] = fv + bv;  // residual + bias folded into C accum
        }
    }
  }
  __syncthreads();

  // ============ C-phase: ffn on f (8 pipelined rounds) ============
  produce_chunk<8, false, 64>(regA, regM, hb0, pn1, bn1, 0, wid, l, lr, lk);
  __syncthreads();
#pragma unroll 1
  for (int r = 0; r < 8; ++r) {
    if (r < 7)
      produce_chunk<8, false, 64>(regA, regM, ((r + 1) & 1) ? hb1 : hb0, pn1,
                                  bn1, r + 1, wid, l, lr, lk);
    consume_chunk((r & 1) ? hb1 : hb0, pn2, r * 4, l, lr, lk, wn, acc2);
    __syncthreads();
  }

  // ---- LN2 in fragment layout -> global out ----
  {
    float mean[2][4], rstd[2][4];
    ln_stats(acc2, mean, rstd);
#pragma unroll
    for (int j = 0; j < 4; ++j) {
      const int col = colb + j * 16 + lr;
      const float gv = fg[col], bv = fb[col];
#pragma unroll
      for (int m = 0; m < 2; ++m)
#pragma unroll
        for (int e = 0; e < 4; ++e) {
          const int row = m * 16 + lk * 4 + e;
          out[(rowbase + row) * 256 + col] =
              (acc2[m][j][e] - mean[m][e]) * rstd[m][e] * gv + bv;
        }
    }
  }
}

}  // namespace

extern "C" void kernel_launch(void* const* d_in, const int* in_sizes, int n_in,
                              void* d_out, int out_size, void* d_ws, size_t ws_size,
                              hipStream_t stream) {
  const float* feats = (const float*)d_in[0];
  const float* boxes = (const float*)d_in[1];
  const void*  masks = d_in[2];
  const int*   times = (const int*)d_in[3];
  const float* wa1 = (const float*)d_in[4];
  const float* ba1 = (const float*)d_in[5];
  const float* wa2 = (const float*)d_in[6];
  const float* ba2 = (const float*)d_in[7];
  const float* ng  = (const float*)d_in[8];
  const float* nb  = (const float*)d_in[9];
  const float* mw1 = (const float*)d_in[10];
  const float* mb1 = (const float*)d_in[11];
  const float* mw2 = (const float*)d_in[12];
  const float* mb2 = (const float*)d_in[13];
  const float* wf1 = (const float*)d_in[14];
  const float* bf1 = (const float*)d_in[15];
  const float* wf2 = (const float*)d_in[16];
  const float* bf2 = (const float*)d_in[17];
  const float* wn1 = (const float*)d_in[18];
  const float* bn1 = (const float*)d_in[19];
  const float* wn2 = (const float*)d_in[20];
  const float* bn2 = (const float*)d_in[21];
  const float* fg  = (const float*)d_in[22];
  const float* fb  = (const float*)d_in[23];

  float* out_fused = (float*)d_out;
  float* out_motion = out_fused + FUSED_N;
  int* flag = (int*)d_ws;
  __bf16* pwp = (__bf16*)((char*)d_ws + 256);

  const int mask_elems = in_sizes[2];  // 153600

  k_zero_flag<<<1, 1, 0, stream>>>(flag);
  k_detect_mask<<<(mask_elems + 255) / 256, 256, 0, stream>>>(
      (const unsigned char*)masks, mask_elems, flag);
  k_motion<<<(BG_ * N_) / 4, 256, 0, stream>>>(boxes, masks, times, mw1, mb1, mw2,
                                               mb2, out_motion, flag);

  auto packn = [&](const float* W, long off, int K, int NN) {
    const int total = (K / 32) * (NN / 16) * 64;
    k_pack<<<(total + 255) / 256, 256, 0, stream>>>(W, pwp + off, K, NN);
  };
  packn(wa1, PA1, 256, 1024);
  packn(wa2, PA2, 1024, 256);
  packn(wf1, PF1, 288, 256);
  packn(wf2, PF2, 256, 256);
  packn(wn1, PN1, 256, 1024);
  packn(wn2, PN2, 1024, 256);

  k_mfma<<<(int)(MROWS_ / MB), 256, 0, stream>>>(
      feats, out_motion, pwp, ba1, ba2, ng, nb, bf1, bf2, bn1, bn2, fg, fb,
      out_fused);
}

// Round 19
// 551.486 us; speedup vs baseline: 1.0318x; 1.0187x over previous
//
#include <hip/hip_runtime.h>

typedef __bf16 bf16x8 __attribute__((ext_vector_type(8)));
typedef __bf16 bf16x4 __attribute__((ext_vector_type(4)));
typedef float f32x4 __attribute__((ext_vector_type(4)));

namespace {

constexpr int T_ = 64;
constexpr int N_ = 300;
constexpr int MD_ = 32;
constexpr int BG_ = 8;                        // B*G
constexpr long MROWS_ = (long)BG_ * T_ * N_;  // 153600
constexpr long FUSED_N = MROWS_ * 256;        // 39321600
constexpr int MB = 32;                        // rows per block (main kernel)

// packed-weight offsets in bf16 elements inside d_ws (after 256-byte header)
constexpr long PA1 = 0;        // adp_w1 [256][1024]
constexpr long PA2 = 262144;   // adp_w2 [1024][256]
constexpr long PF1 = 524288;   // fus_w1 [288][256]
constexpr long PF2 = 598016;   // fus_w2 [256][256]
constexpr long PN1 = 663552;   // ffn_w1 [256][1024]
constexpr long PN2 = 925696;   // ffn_w2 [1024][256]

// fused-prep block ranges: [0,600) motion; then packs (exact multiples)
constexpr int MOT_B = 600;                    // (BG_*N_)/4
constexpr int PA1_B = 128, PA2_B = 128, PF1_B = 36, PF2_B = 32, PN1_B = 128,
              PN2_B = 128;
constexpr int PREP_B = MOT_B + PA1_B + PA2_B + PF1_B + PF2_B + PN1_B + PN2_B;

// fast tanh-form GELU: |delta| vs erf-GELU <= ~2e-3 (under bf16 noise)
__device__ __forceinline__ float gelu_f(float x) {
  const float x2 = x * x;
  const float z2 = x * fmaf(x2, 0.07135481627f, 1.5957691216f);  // 2*z
  const float t = __builtin_amdgcn_rcpf(1.0f + __expf(z2));      // (1-tanh z)/2
  return x * (1.0f - t);
}

__device__ __forceinline__ float gelu_exact(float x) {
  return 0.5f * x * (1.0f + erff(x * 0.7071067811865476f));
}

// ---------------- mask dtype detection ----------------
__global__ void k_zero_flag(int* f) { *f = 0; }

__global__ void k_detect_mask(const unsigned char* __restrict__ m, int nbytes,
                              int* __restrict__ f) {
  int i = blockIdx.x * 256 + threadIdx.x;
  if (i < nbytes && (i & 3) != 0 && m[i] != 0) atomicOr(f, 1);
}

// ---------------- fused prep kernel: motion + all 6 weight packs ----------
// R28: collapses 7 independent launches (motion + 6x k_pack) into one
// 1180-block kernel -- removes 6 graph-node launch overheads and lets the
// small pack blocks fill CUs alongside motion. Bodies are byte-identical
// to the R27-verified k_motion / k_pack; only the block-id mapping is new.
__global__ __launch_bounds__(256)
void k_prep(const float* __restrict__ boxes, const void* __restrict__ masks,
            const int* __restrict__ times,
            const float* __restrict__ mw1, const float* __restrict__ mb1,
            const float* __restrict__ mw2, const float* __restrict__ mb2,
            float* __restrict__ motion, const int* __restrict__ flagp,
            const float* __restrict__ wa1, const float* __restrict__ wa2,
            const float* __restrict__ wf1, const float* __restrict__ wf2,
            const float* __restrict__ wn1, const float* __restrict__ wn2,
            __bf16* __restrict__ pw) {
  const int tid = threadIdx.x;
  int bid = blockIdx.x;

  if (bid < MOT_B) {
    // ---------------- motion features (verified body) ----------------
    __shared__ int slot[4][T_];
    __shared__ int sts[4][T_];
    __shared__ float sbx[4][T_][4];
    __shared__ float otile[4][T_][MD_];
    const int w = tid >> 6, l = tid & 63;
    const int traj = bid * 4 + w;
    const int bg = traj / N_, n = traj - bg * N_;
    const int isbool = *flagp;
    const long idx = ((long)bg * T_ + l) * N_ + n;  // t = l
    const bool msk = isbool ? (((const unsigned char*)masks)[idx] != 0)
                            : (((const int*)masks)[idx] != 0);
    const bool valid = !msk;
    const int tm = times[idx];

    slot[w][l] = -1;
    sts[w][l] = 0;
    *(float4*)&sbx[w][l][0] = make_float4(0.f, 0.f, 0.f, 0.f);
    __syncthreads();
    if (valid) slot[w][tm] = l;
    __syncthreads();

    const int ot = slot[w][l];
    const bool vp = ot >= 0;
    const unsigned long long bal = __ballot(vp);
    const int cnt = __builtin_popcountll(bal);
    const int pos = __builtin_popcountll(bal & ((1ull << l) - 1ull));
    if (vp) {
      sts[w][pos] = l;
      const float4 bx =
          *(const float4*)(boxes + (((long)bg * T_ + ot) * N_ + n) * 4);
      *(float4*)&sbx[w][pos][0] = bx;
    }
    __syncthreads();

    const int stp = sts[w][l];
    const int stm1 = sts[w][(l + 63) & 63];
    const float4 sb = *(const float4*)&sbx[w][l][0];
    const float4 sbm = *(const float4*)&sbx[w][(l + 63) & 63][0];
    const float dt = (float)max(stp - stm1, 1);
    const float inv = 1.0f / dt;
    const bool okv = (l >= 1) && (l < cnt);
    float v0 = okv ? (sb.x - sbm.x) * inv : 0.f;
    float v1 = okv ? (sb.y - sbm.y) * inv : 0.f;
    float v2 = okv ? (sb.z - sbm.z) * inv : 0.f;
    float v3 = okv ? (sb.w - sbm.w) * inv : 0.f;
    const float p0 = __shfl_up(v0, 1, 64);
    const float p1 = __shfl_up(v1, 1, 64);
    const float p2 = __shfl_up(v2, 1, 64);
    const float p3 = __shfl_up(v3, 1, 64);
    const bool oka = (l >= 2) && (l < cnt);
    const float a0 = oka ? (v0 - p0) * inv : 0.f;
    const float a1 = oka ? (v1 - p1) * inv : 0.f;
    const float a2 = oka ? (v2 - p2) * inv : 0.f;
    const float a3 = oka ? (v3 - p3) * inv : 0.f;

    const float mv[12] = {sb.x, sb.y, sb.z, sb.w, v0, v1,
                          v2,   v3,   a0,   a1,   a2, a3};
    float e1[16];
#pragma unroll
    for (int i = 0; i < 16; ++i) {
      float a = mb1[i];
#pragma unroll
      for (int c = 0; c < 12; ++c) a = fmaf(mv[c], mw1[c * 16 + i], a);
      e1[i] = gelu_exact(a);
    }
    float enc[32];
#pragma unroll
    for (int o = 0; o < 32; ++o) {
      float a = mb2[o];
#pragma unroll
      for (int i = 0; i < 16; ++i) a = fmaf(e1[i], mw2[i * 32 + o], a);
      enc[o] = a;
    }

#pragma unroll
    for (int c = 0; c < 32; c += 4)
      *(float4*)&otile[w][l][c] = make_float4(0.f, 0.f, 0.f, 0.f);
    __syncthreads();
    if (l < cnt && cnt >= 2) {
#pragma unroll
      for (int c = 0; c < 32; ++c) otile[w][stp][c] = enc[c];
    }
    __syncthreads();

    float* mbase = motion + ((long)bg * T_ * N_ + n) * MD_;
    const float4* srcv = (const float4*)&otile[w][l][0];
    float4* dstv = (float4*)(mbase + (long)l * N_ * MD_);
#pragma unroll
    for (int q = 0; q < 8; ++q) dstv[q] = srcv[q];
    return;
  }

  // ---------------- weight packing (verified body) ----------------
  // frag f = kb*(NN/16)+nt holds W[kb*32 + (l>>4)*8 + e][nt*16 + (l&15)],
  // stored lane-contiguous: P[(f*64 + l)*8 + e].
  bid -= MOT_B;
  const float* W;
  long off;
  int K, NN;
  if (bid < PA1_B) {
    W = wa1; off = PA1; K = 256; NN = 1024;
  } else if (bid < PA1_B + PA2_B) {
    bid -= PA1_B; W = wa2; off = PA2; K = 1024; NN = 256;
  } else if (bid < PA1_B + PA2_B + PF1_B) {
    bid -= PA1_B + PA2_B; W = wf1; off = PF1; K = 288; NN = 256;
  } else if (bid < PA1_B + PA2_B + PF1_B + PF2_B) {
    bid -= PA1_B + PA2_B + PF1_B; W = wf2; off = PF2; K = 256; NN = 256;
  } else if (bid < PA1_B + PA2_B + PF1_B + PF2_B + PN1_B) {
    bid -= PA1_B + PA2_B + PF1_B + PF2_B; W = wn1; off = PN1; K = 256;
    NN = 1024;
  } else {
    bid -= PA1_B + PA2_B + PF1_B + PF2_B + PN1_B; W = wn2; off = PN2;
    K = 1024; NN = 256;
  }
  __bf16* P = pw + off;
  const int gid = bid * 256 + tid;  // ranges are exact multiples of 256
  const int l = gid & 63, f = gid >> 6;
  const int NT = NN >> 4;
  const int kb = f / NT, nt = f - kb * NT;
  const int krow = kb * 32 + (l >> 4) * 8;
  const int col = nt * 16 + (l & 15);
  bf16x8 v;
#pragma unroll
  for (int e = 0; e < 8; ++e) v[e] = (__bf16)W[(long)(krow + e) * NN + col];
  *(bf16x8*)(P + (long)gid * 8) = v;
}

// ---- swapped-orientation producer: one [32 rows]x[128 feat] gelu'd chunk ----
// Each wave owns TWO 16-feat tiles (nt0 = r*8 + wid*2, +1): the same xf
// ds_read feeds 4 MFMAs (2 nt x 2 rt). Weight loads double-buffered 2 kb
// ahead (verified R22). C-layout lane holds (x-row = l&15, 4 consecutive
// feats) -> one packed ds_write_b64 per (nt, rt) into hb[row][feat] (row
// stride 256B, byte ^ ((row&7)<<4) swizzle -- the R14-verified pattern).
// K = NKB*32; if MOT, last kb reads the motion tile (regM) instead of regA.
template <int NKB, bool MOT, int NT>
__device__ __forceinline__ void produce_chunk(
    const char* regA, const char* regM, char* hb, const __bf16* pb1,
    const float* b1, int r, int wid, int l, int lr, int lk) {
  const int nt0 = r * 8 + wid * 2;
  f32x4 t[2][2];  // [n][rt]
#pragma unroll
  for (int n = 0; n < 2; ++n) {
    const float4 bv = *(const float4*)(b1 + (nt0 + n) * 16 + lk * 4);
    t[n][0] = f32x4{bv.x, bv.y, bv.z, bv.w};
    t[n][1] = t[n][0];
  }
  const __bf16* wp0 = pb1 + ((long)nt0 << 9) + (l << 3);
  const __bf16* wp1 = wp0 + (1 << 9);
  bf16x8 wa0 = *(const bf16x8*)(wp0);
  bf16x8 wa1 = *(const bf16x8*)(wp1);
  bf16x8 wb0 = wa0, wb1 = wa1;
  if (NKB > 1) {
    wb0 = *(const bf16x8*)(wp0 + ((long)NT << 9));
    wb1 = *(const bf16x8*)(wp1 + ((long)NT << 9));
  }
#pragma unroll
  for (int kb = 0; kb < NKB; ++kb) {
    const bf16x8 wf0 = (kb & 1) ? wb0 : wa0;
    const bf16x8 wf1 = (kb & 1) ? wb1 : wa1;
    if (kb + 2 < NKB) {
      const bf16x8 v0 = *(const bf16x8*)(wp0 + ((long)((kb + 2) * NT) << 9));
      const bf16x8 v1 = *(const bf16x8*)(wp1 + ((long)((kb + 2) * NT) << 9));
      if (kb & 1) { wb0 = v0; wb1 = v1; } else { wa0 = v0; wa1 = v1; }
    }
    __builtin_amdgcn_s_setprio(1);
#pragma unroll
    for (int rt = 0; rt < 2; ++rt) {
      const int row = rt * 16 + lr;
      bf16x8 xf;
      if (MOT && kb == NKB - 1)
        xf = *(const bf16x8*)(regM + row * 64 + ((lk ^ (row & 3)) << 4));
      else
        xf = *(const bf16x8*)(regA + row * 512 +
                              ((((kb << 2) + lk) ^ (row & 7)) << 4));
      t[0][rt] = __builtin_amdgcn_mfma_f32_16x16x32_bf16(wf0, xf, t[0][rt], 0, 0, 0);
      t[1][rt] = __builtin_amdgcn_mfma_f32_16x16x32_bf16(wf1, xf, t[1][rt], 0, 0, 0);
    }
    __builtin_amdgcn_s_setprio(0);
  }
#pragma unroll
  for (int n = 0; n < 2; ++n)
#pragma unroll
    for (int rt = 0; rt < 2; ++rt) {
      const int row = rt * 16 + lr;
      bf16x4 hv;
#pragma unroll
      for (int e = 0; e < 4; ++e) hv[e] = (__bf16)gelu_f(t[n][rt][e]);
      *(bf16x4*)(hb + row * 256 +
                 ((wid * 64 + n * 32 + lk * 8) ^ ((row & 7) << 4))) = hv;
    }
}

// ---- normal-orientation consumer: acc += chunk(K=128) @ pb2[slice][wn] ----
// A-frags via ds_read_b128 from hb (same byte-XOR swizzle as produce),
// weights direct from global (L2), double-buffered (R25-verified).
__device__ __forceinline__ void consume_chunk(const char* hb,
                                              const __bf16* pb2, int kbg0,
                                              int l, int lr, int lk, int wn,
                                              f32x4 (&acc)[2][4]) {
  const __bf16* wp = pb2 + ((long)(kbg0 * 16 + wn * 4) << 9) + (l << 3);
  bf16x8 bw0[4], bw1[4];
#pragma unroll
  for (int j = 0; j < 4; ++j) bw0[j] = *(const bf16x8*)(wp + ((long)j << 9));
#pragma unroll
  for (int kbl = 0; kbl < 4; ++kbl) {
    if (kbl < 3) {
#pragma unroll
      for (int j = 0; j < 4; ++j)
        bw1[j] = *(const bf16x8*)(wp + ((long)((kbl + 1) * 16 + j) << 9));
    }
    bf16x8 a[2];
#pragma unroll
    for (int m = 0; m < 2; ++m) {
      const int row = m * 16 + lr;
      a[m] = *(const bf16x8*)(hb + row * 256 +
                              ((kbl * 64 + lk * 16) ^ ((row & 7) << 4)));
    }
    __builtin_amdgcn_s_setprio(1);
#pragma unroll
    for (int j = 0; j < 4; ++j)
#pragma unroll
      for (int m = 0; m < 2; ++m)
        acc[m][j] = __builtin_amdgcn_mfma_f32_16x16x32_bf16(a[m], bw0[j],
                                                            acc[m][j], 0, 0, 0);
    __builtin_amdgcn_s_setprio(0);
#pragma unroll
    for (int j = 0; j < 4; ++j) bw0[j] = bw1[j];
  }
}

// ---------------- fused MFMA row pipeline (R27-verified optimum) ----------
// MB=32, 256 threads, (256,3) -> 170 unified regs (unique spill-free
// point), produce widened 2-nt, consume weight double-buffer. Traffic at
// ideal (FETCH 206 / WRITE 201 MB), conflicts at the ds_read_b128-inherent
// level, MfmaUtil ~30 / VALU ~39 / HBM ~9%: latency plateau of this
// decomposition -- every tested perturbation regresses (R10-R26).
__global__ __launch_bounds__(256, 3)
void k_mfma(const float* __restrict__ feats, const float* __restrict__ motion,
            const __bf16* __restrict__ pw,
            const float* __restrict__ ba1, const float* __restrict__ ba2,
            const float* __restrict__ ng, const float* __restrict__ nb,
            const float* __restrict__ bf1, const float* __restrict__ bf2,
            const float* __restrict__ bn1, const float* __restrict__ bn2,
            const float* __restrict__ fg, const float* __restrict__ fb,
            float* __restrict__ out) {
  __shared__ __align__(16) char smem[35840];
  char* regA = smem;             // [32][256] bf16 swizzled: x / LN1 / f
  char* hb0 = smem + 16384;      // h/g1 chunk buffer 0: [32][128] bf16
  char* hb1 = smem + 24576;      // h/g1 chunk buffer 1
  char* regM = smem + 32768;     // [32][32] bf16 motion tile
  float* redp = (float*)(smem + 34816);  // [32][4][2] LN partials

  const int tid = threadIdx.x;
  const int l = tid & 63, wid = tid >> 6;  // 4 waves
  const int lr = l & 15, lk = l >> 4;
  const int wn = wid;          // 0..3 : 64-col slice (consume)
  const int colb = wn * 64;
  const long rowbase = (long)blockIdx.x * MB;

  const __bf16* pa1 = pw + PA1;
  const __bf16* pa2 = pw + PA2;
  const __bf16* pf1 = pw + PF1;
  const __bf16* pf2 = pw + PF2;
  const __bf16* pn1 = pw + PN1;
  const __bf16* pn2 = pw + PN2;

  // fragment-layout LN stats: mean/rstd per owned row (m,e)
  auto ln_stats = [&](const f32x4 (&acc)[2][4], float (&mean)[2][4],
                      float (&rstd)[2][4]) {
    float s1[2][4], s2[2][4];
#pragma unroll
    for (int m = 0; m < 2; ++m)
#pragma unroll
      for (int e = 0; e < 4; ++e) { s1[m][e] = 0.f; s2[m][e] = 0.f; }
#pragma unroll
    for (int m = 0; m < 2; ++m)
#pragma unroll
      for (int j = 0; j < 4; ++j)
#pragma unroll
        for (int e = 0; e < 4; ++e) {
          s1[m][e] += acc[m][j][e];
          s2[m][e] += acc[m][j][e] * acc[m][j][e];
        }
#pragma unroll
    for (int o = 1; o < 16; o <<= 1)
#pragma unroll
      for (int m = 0; m < 2; ++m)
#pragma unroll
        for (int e = 0; e < 4; ++e) {
          s1[m][e] += __shfl_xor(s1[m][e], o);
          s2[m][e] += __shfl_xor(s2[m][e], o);
        }
    if (lr == 0) {
#pragma unroll
      for (int m = 0; m < 2; ++m)
#pragma unroll
        for (int e = 0; e < 4; ++e) {
          const int row = m * 16 + lk * 4 + e;
          redp[(row * 4 + wn) * 2 + 0] = s1[m][e];
          redp[(row * 4 + wn) * 2 + 1] = s2[m][e];
        }
    }
    __syncthreads();
#pragma unroll
    for (int m = 0; m < 2; ++m)
#pragma unroll
      for (int e = 0; e < 4; ++e) {
        const int row = m * 16 + lk * 4 + e;
        const float S1 = redp[(row * 4 + 0) * 2] + redp[(row * 4 + 1) * 2] +
                         redp[(row * 4 + 2) * 2] + redp[(row * 4 + 3) * 2];
        const float S2 = redp[(row * 4 + 0) * 2 + 1] + redp[(row * 4 + 1) * 2 + 1] +
                         redp[(row * 4 + 2) * 2 + 1] + redp[(row * 4 + 3) * 2 + 1];
        const float mu = S1 * (1.0f / 256.0f);
        const float var = S2 * (1.0f / 256.0f) - mu * mu;
        mean[m][e] = mu;
        rstd[m][e] = rsqrtf(var + 1e-5f);
      }
  };

  f32x4 acc2[2][4];
  // ---- init acc2 = x + ba2 (residual + bias folded into accumulator) ----
#pragma unroll
  for (int j = 0; j < 4; ++j) {
    const int col = colb + j * 16 + lr;
    const float bv = ba2[col];
#pragma unroll
    for (int m = 0; m < 2; ++m)
#pragma unroll
      for (int e = 0; e < 4; ++e) {
        const int row = m * 16 + lk * 4 + e;
        acc2[m][j][e] = bv + feats[(rowbase + row) * 256 + col];
      }
  }
  // ---- stage x (bf16, swizzled) into regA ----
#pragma unroll
  for (int it = 0; it < 4; ++it) {
    const int c = tid + it * 256;  // chunk id, 1024 total
    const int row = c >> 5, cc = c & 31;
    const float* src = feats + (rowbase + row) * 256 + cc * 8;
    bf16x8 v;
#pragma unroll
    for (int e = 0; e < 8; ++e) v[e] = (__bf16)src[e];
    *(bf16x8*)(regA + row * 512 + ((cc ^ (row & 7)) << 4)) = v;
  }
  __syncthreads();

  // ============ A-phase: x -> h -> adp out (8 pipelined rounds) ============
  produce_chunk<8, false, 64>(regA, regM, hb0, pa1, ba1, 0, wid, l, lr, lk);
  __syncthreads();
#pragma unroll 1
  for (int r = 0; r < 8; ++r) {
    if (r < 7)
      produce_chunk<8, false, 64>(regA, regM, ((r + 1) & 1) ? hb1 : hb0, pa1,
                                  ba1, r + 1, wid, l, lr, lk);
    consume_chunk((r & 1) ? hb1 : hb0, pa2, r * 4, l, lr, lk, wn, acc2);
    __syncthreads();
  }

  // ---- LN1 in fragment layout -> regA bf16; stage motion -> regM ----
  {
    float mean[2][4], rstd[2][4];
    ln_stats(acc2, mean, rstd);
#pragma unroll
    for (int j = 0; j < 4; ++j) {
      const int col = colb + j * 16 + lr;
      const float gv = ng[col], bv = nb[col];
#pragma unroll
      for (int m = 0; m < 2; ++m)
#pragma unroll
        for (int e = 0; e < 4; ++e) {
          const int row = m * 16 + lk * 4 + e;
          const float v = (acc2[m][j][e] - mean[m][e]) * rstd[m][e] * gv + bv;
          *(__bf16*)(regA + row * 512 + (((col >> 3) ^ (row & 7)) << 4) +
                     ((col & 7) << 1)) = (__bf16)v;
        }
    }
    if (tid < 128) {  // motion tile -> regM; 32x32 bf16
      const int row = tid >> 2, cc = tid & 3;
      const float* src = motion + (rowbase + row) * 32 + cc * 8;
      bf16x8 v;
#pragma unroll
      for (int e = 0; e < 8; ++e) v[e] = (__bf16)src[e];
      *(bf16x8*)(regM + row * 64 + ((cc ^ (row & 3)) << 4)) = v;
    }
  }
  __syncthreads();

  // ====== B-phase: fus MLP (2 pipelined rounds, K=288 w/ motion) ======
  // acc2's A-phase value is DEAD here (consumed by ln_stats/LN1 above) --
  // reused as the B2 accumulator (R19).
  {
#pragma unroll
    for (int j = 0; j < 4; ++j) {
      const float bv = bf2[colb + j * 16 + lr];
#pragma unroll
      for (int m = 0; m < 2; ++m) acc2[m][j] = {bv, bv, bv, bv};
    }
    produce_chunk<9, true, 16>(regA, regM, hb0, pf1, bf1, 0, wid, l, lr, lk);
    __syncthreads();
    produce_chunk<9, true, 16>(regA, regM, hb1, pf1, bf1, 1, wid, l, lr, lk);
    consume_chunk(hb0, pf2, 0, l, lr, lk, wn, acc2);
    __syncthreads();
    consume_chunk(hb1, pf2, 4, l, lr, lk, wn, acc2);
    __syncthreads();
    // tail: f -> regA (C1 input, bf16) ; acc2 = f + bn2 (in place)
#pragma unroll
    for (int j = 0; j < 4; ++j) {
      const int col = colb + j * 16 + lr;
      const float bv = bn2[col];
#pragma unroll
      for (int m = 0; m < 2; ++m)
#pragma unroll
        for (int e = 0; e < 4; ++e) {
          const int row = m * 16 + lk * 4 + e;
          const float fv = acc2[m][j][e];
          *(__bf16*)(regA + row * 512 + (((col >> 3) ^ (row & 7)) << 4) +
                     ((col & 7) << 1)) = (__bf16)fv;  // C1 input
          acc2[m][j][e] = fv + bv;  // residual + bias folded into C accum
        }
    }
  }
  __syncthreads();

  // ============ C-phase: ffn on f (8 pipelined rounds) ============
  produce_chunk<8, false, 64>(regA, regM, hb0, pn1, bn1, 0, wid, l, lr, lk);
  __syncthreads();
#pragma unroll 1
  for (int r = 0; r < 8; ++r) {
    if (r < 7)
      produce_chunk<8, false, 64>(regA, regM, ((r + 1) & 1) ? hb1 : hb0, pn1,
                                  bn1, r + 1, wid, l, lr, lk);
    consume_chunk((r & 1) ? hb1 : hb0, pn2, r * 4, l, lr, lk, wn, acc2);
    __syncthreads();
  }

  // ---- LN2 in fragment layout -> global out ----
  {
    float mean[2][4], rstd[2][4];
    ln_stats(acc2, mean, rstd);
#pragma unroll
    for (int j = 0; j < 4; ++j) {
      const int col = colb + j * 16 + lr;
      const float gv = fg[col], bv = fb[col];
#pragma unroll
      for (int m = 0; m < 2; ++m)
#pragma unroll
        for (int e = 0; e < 4; ++e) {
          const int row = m * 16 + lk * 4 + e;
          out[(rowbase + row) * 256 + col] =
              (acc2[m][j][e] - mean[m][e]) * rstd[m][e] * gv + bv;
        }
    }
  }
}

}  // namespace

extern "C" void kernel_launch(void* const* d_in, const int* in_sizes, int n_in,
                              void* d_out, int out_size, void* d_ws, size_t ws_size,
                              hipStream_t stream) {
  const float* feats = (const float*)d_in[0];
  const float* boxes = (const float*)d_in[1];
  const void*  masks = d_in[2];
  const int*   times = (const int*)d_in[3];
  const float* wa1 = (const float*)d_in[4];
  const float* ba1 = (const float*)d_in[5];
  const float* wa2 = (const float*)d_in[6];
  const float* ba2 = (const float*)d_in[7];
  const float* ng  = (const float*)d_in[8];
  const float* nb  = (const float*)d_in[9];
  const float* mw1 = (const float*)d_in[10];
  const float* mb1 = (const float*)d_in[11];
  const float* mw2 = (const float*)d_in[12];
  const float* mb2 = (const float*)d_in[13];
  const float* wf1 = (const float*)d_in[14];
  const float* bf1 = (const float*)d_in[15];
  const float* wf2 = (const float*)d_in[16];
  const float* bf2 = (const float*)d_in[17];
  const float* wn1 = (const float*)d_in[18];
  const float* bn1 = (const float*)d_in[19];
  const float* wn2 = (const float*)d_in[20];
  const float* bn2 = (const float*)d_in[21];
  const float* fg  = (const float*)d_in[22];
  const float* fb  = (const float*)d_in[23];

  float* out_fused = (float*)d_out;
  float* out_motion = out_fused + FUSED_N;
  int* flag = (int*)d_ws;
  __bf16* pwp = (__bf16*)((char*)d_ws + 256);

  const int mask_elems = in_sizes[2];  // 153600

  k_zero_flag<<<1, 1, 0, stream>>>(flag);
  k_detect_mask<<<(mask_elems + 255) / 256, 256, 0, stream>>>(
      (const unsigned char*)masks, mask_elems, flag);
  // fused prep: motion + all 6 weight packs in ONE launch (R28)
  k_prep<<<PREP_B, 256, 0, stream>>>(boxes, masks, times, mw1, mb1, mw2, mb2,
                                     out_motion, flag, wa1, wa2, wf1, wf2, wn1,
                                     wn2, pwp);
  k_mfma<<<(int)(MROWS_ / MB), 256, 0, stream>>>(
      feats, out_motion, pwp, ba1, ba2, ng, nb, bf1, bf2, bn1, bn2, fg, fb,
      out_fused);
}